// Round 2
// baseline (3363.306 us; speedup 1.0000x reference)
//
#include <hip/hip_runtime.h>
#include <math.h>

#define BATCH   131072
#define IN_F    80
#define EMB     64
#define NE      16
#define RANK    8
#define UDIM    16
#define NCLS    10
#define NUSERS  1000
#define W2P     12   // padded e_w2 row (10 -> 12 floats for float4 alignment)

// ---- workspace layout (bytes) ----
#define OFF_H      0ull                 // BATCH*64 f32      = 33554432
#define OFF_A      33554432ull          // NUSERS*16*64 f32  =  4096000
#define OFF_TOPE   37650432ull          // 2*BATCH int       =  1048576
#define OFF_TOPW   38699008ull          // 2*BATCH f32       =  1048576
#define OFF_PAIRB  39747584ull          // 2*BATCH int       =  1048576
#define OFF_PAIRW  40796160ull          // 2*BATCH f32       =  1048576
#define OFF_HIST   41844736ull
#define OFF_OFFS   41845760ull
#define OFF_CUR    41846784ull

__device__ __forceinline__ float gelu_f(float v) {
    return 0.5f * v * (1.0f + erff(v * 0.70710678118654752440f));
}

// ---------------- A[u][e][d] = sum_r gU[e][d][r] * (sum_dd ut[u][dd]*gV[e][dd][r]) ----------------
__global__ void k_prep(const float* __restrict__ gU, const float* __restrict__ gV,
                       const float* __restrict__ ut, float* __restrict__ A)
{
    int idx = blockIdx.x * 256 + threadIdx.x;
    if (idx >= NUSERS * NE) return;
    int u = idx / NE, e = idx - u * NE;

    float uvec[UDIM];
    const float4* up = (const float4*)(ut + (size_t)u * UDIM);
#pragma unroll
    for (int t = 0; t < UDIM / 4; ++t) {
        float4 v = up[t];
        uvec[4*t+0] = v.x; uvec[4*t+1] = v.y; uvec[4*t+2] = v.z; uvec[4*t+3] = v.w;
    }

    float uv[RANK];
#pragma unroll
    for (int r = 0; r < RANK; ++r) uv[r] = 0.0f;
    const float4* gv4 = (const float4*)gV;
#pragma unroll
    for (int dd = 0; dd < UDIM; ++dd) {
        float4 g0 = gv4[(e * UDIM + dd) * 2 + 0];
        float4 g1 = gv4[(e * UDIM + dd) * 2 + 1];
        float ud = uvec[dd];
        uv[0] = fmaf(ud, g0.x, uv[0]); uv[1] = fmaf(ud, g0.y, uv[1]);
        uv[2] = fmaf(ud, g0.z, uv[2]); uv[3] = fmaf(ud, g0.w, uv[3]);
        uv[4] = fmaf(ud, g1.x, uv[4]); uv[5] = fmaf(ud, g1.y, uv[5]);
        uv[6] = fmaf(ud, g1.z, uv[6]); uv[7] = fmaf(ud, g1.w, uv[7]);
    }

    const float4* gu4 = (const float4*)gU;
    float4* Ao = (float4*)(A + ((size_t)u * NE + e) * EMB);
#pragma unroll
    for (int d4 = 0; d4 < EMB / 4; ++d4) {
        float4 o;
        float* op = (float*)&o;
#pragma unroll
        for (int j = 0; j < 4; ++j) {
            int d = 4 * d4 + j;
            float4 q0 = gu4[(e * EMB + d) * 2 + 0];
            float4 q1 = gu4[(e * EMB + d) * 2 + 1];
            float a = 0.0f;
            a = fmaf(q0.x, uv[0], a); a = fmaf(q0.y, uv[1], a);
            a = fmaf(q0.z, uv[2], a); a = fmaf(q0.w, uv[3], a);
            a = fmaf(q1.x, uv[4], a); a = fmaf(q1.y, uv[5], a);
            a = fmaf(q1.z, uv[6], a); a = fmaf(q1.w, uv[7], a);
            op[j] = a;
        }
        Ao[d4] = o;
    }
}

// ---------------- fused: backbone (fc1+gelu, fc2+gelu, LN) + gate + softmax + top2 ----------------
__global__ __launch_bounds__(256, 2) void k_fused(
    const float* __restrict__ x, const int* __restrict__ uid,
    const float* __restrict__ w1, const float* __restrict__ b1,
    const float* __restrict__ w2, const float* __restrict__ b2,
    const float* __restrict__ gam, const float* __restrict__ bet,
    const float* __restrict__ A, const float* __restrict__ gb,
    float* __restrict__ h_out,
    int* __restrict__ top_e, float* __restrict__ top_w, int* __restrict__ hist)
{
    __shared__ __align__(16) float s_w1[IN_F * EMB];   // 20 KB
    __shared__ __align__(16) float s_w2[EMB * EMB];    // 16 KB
    __shared__ __align__(16) float s_b1[EMB];
    __shared__ __align__(16) float s_b2[EMB];
    __shared__ __align__(16) float s_gam[EMB];
    __shared__ __align__(16) float s_bet[EMB];
    __shared__ int s_hist[NE];

    const int tid = threadIdx.x;
    for (int i = tid; i < IN_F * EMB; i += 256) s_w1[i] = w1[i];
    for (int i = tid; i < EMB * EMB; i += 256) s_w2[i] = w2[i];
    if (tid < EMB) { s_b1[tid] = b1[tid]; s_b2[tid] = b2[tid]; s_gam[tid] = gam[tid]; s_bet[tid] = bet[tid]; }
    if (tid < NE) s_hist[tid] = 0;
    __syncthreads();

    const int b = blockIdx.x * 256 + tid;

    float xf[IN_F];
    const float4* xp = (const float4*)(x + (size_t)b * IN_F);
#pragma unroll
    for (int t = 0; t < IN_F / 4; ++t) {
        float4 v = xp[t];
        xf[4*t+0] = v.x; xf[4*t+1] = v.y; xf[4*t+2] = v.z; xf[4*t+3] = v.w;
    }

    float h1[EMB];
    {
        const float4* sw = (const float4*)s_w1;
        const float4* sb = (const float4*)s_b1;
#pragma unroll
        for (int k0 = 0; k0 < EMB / 4; ++k0) {
            float4 a = sb[k0];
#pragma unroll
            for (int d = 0; d < IN_F; ++d) {
                float4 w = sw[d * (EMB / 4) + k0];
                a.x = fmaf(xf[d], w.x, a.x);
                a.y = fmaf(xf[d], w.y, a.y);
                a.z = fmaf(xf[d], w.z, a.z);
                a.w = fmaf(xf[d], w.w, a.w);
            }
            h1[4*k0+0] = gelu_f(a.x); h1[4*k0+1] = gelu_f(a.y);
            h1[4*k0+2] = gelu_f(a.z); h1[4*k0+3] = gelu_f(a.w);
        }
    }

    float hv[EMB];
    {
        const float4* sw = (const float4*)s_w2;
        const float4* sb = (const float4*)s_b2;
#pragma unroll
        for (int k0 = 0; k0 < EMB / 4; ++k0) {
            float4 a = sb[k0];
#pragma unroll
            for (int d = 0; d < EMB; ++d) {
                float4 w = sw[d * (EMB / 4) + k0];
                a.x = fmaf(h1[d], w.x, a.x);
                a.y = fmaf(h1[d], w.y, a.y);
                a.z = fmaf(h1[d], w.z, a.z);
                a.w = fmaf(h1[d], w.w, a.w);
            }
            hv[4*k0+0] = gelu_f(a.x); hv[4*k0+1] = gelu_f(a.y);
            hv[4*k0+2] = gelu_f(a.z); hv[4*k0+3] = gelu_f(a.w);
        }
    }

    // LayerNorm
    float mu = 0.0f;
#pragma unroll
    for (int k = 0; k < EMB; ++k) mu += hv[k];
    mu *= (1.0f / EMB);
    float var = 0.0f;
#pragma unroll
    for (int k = 0; k < EMB; ++k) { float t = hv[k] - mu; var = fmaf(t, t, var); }
    var *= (1.0f / EMB);
    float inv = 1.0f / sqrtf(var + 1e-5f);
#pragma unroll
    for (int k = 0; k < EMB; ++k) hv[k] = (hv[k] - mu) * inv * s_gam[k] + s_bet[k];

    // write h (fp32) for expert stage
    {
        float4* ho = (float4*)(h_out + (size_t)b * EMB);
#pragma unroll
        for (int k0 = 0; k0 < EMB / 4; ++k0) {
            float4 o;
            o.x = hv[4*k0+0]; o.y = hv[4*k0+1]; o.z = hv[4*k0+2]; o.w = hv[4*k0+3];
            ho[k0] = o;
        }
    }

    // gate: g[e] = dot(hv, A[u][e][:]) + gb[e]
    const int u = uid[b];
    const float* Arow = A + (size_t)u * NE * EMB;
    float g[NE];
#pragma unroll
    for (int e = 0; e < NE; ++e) {
        const float4* ap = (const float4*)(Arow + e * EMB);
        float4 acc = make_float4(0.f, 0.f, 0.f, 0.f);
#pragma unroll
        for (int t = 0; t < EMB / 4; ++t) {
            float4 a4 = ap[t];
            acc.x = fmaf(hv[4*t+0], a4.x, acc.x);
            acc.y = fmaf(hv[4*t+1], a4.y, acc.y);
            acc.z = fmaf(hv[4*t+2], a4.z, acc.z);
            acc.w = fmaf(hv[4*t+3], a4.w, acc.w);
        }
        g[e] = (acc.x + acc.y) + (acc.z + acc.w) + gb[e];
    }

    // softmax (stable) — same numerics as validated round-0 path
    float m = g[0];
#pragma unroll
    for (int e = 1; e < NE; ++e) m = fmaxf(m, g[e]);
    float w[NE];
    float s = 0.0f;
#pragma unroll
    for (int e = 0; e < NE; ++e) { w[e] = expf(g[e] - m); s += w[e]; }
    float sinv = 1.0f / s;
#pragma unroll
    for (int e = 0; e < NE; ++e) w[e] *= sinv;

    // top-2, first (lowest) index wins ties
    int i0 = 0; float b0 = w[0];
#pragma unroll
    for (int e = 1; e < NE; ++e) { if (w[e] > b0) { b0 = w[e]; i0 = e; } }
    int i1 = (i0 == 0) ? 1 : 0; float b1v = w[i1];
#pragma unroll
    for (int e = 0; e < NE; ++e) {
        if (e != i0 && w[e] > b1v) { b1v = w[e]; i1 = e; }
    }
    float denom = fmaxf(b0 + b1v, 1e-9f);
    float w0n = b0 / denom, w1n = b1v / denom;

    top_e[2*b+0] = i0; top_w[2*b+0] = w0n;
    top_e[2*b+1] = i1; top_w[2*b+1] = w1n;
    atomicAdd(&s_hist[i0], 1);
    atomicAdd(&s_hist[i1], 1);
    __syncthreads();
    if (tid < NE) atomicAdd(&hist[tid], s_hist[tid]);
}

// ---------------- tiny exclusive scan over 16 bins ----------------
__global__ void k_scan(const int* __restrict__ hist, int* __restrict__ offs, int* __restrict__ cur)
{
    if (blockIdx.x == 0 && threadIdx.x == 0) {
        int acc = 0;
        for (int e = 0; e < NE; ++e) { offs[e] = acc; cur[e] = acc; acc += hist[e]; }
    }
}

// ---------------- block-aggregated scatter into expert buckets ----------------
__global__ __launch_bounds__(256) void k_scatter(
    const int* __restrict__ top_e, const float* __restrict__ top_w,
    int* __restrict__ cur, int* __restrict__ pair_b, float* __restrict__ pair_w)
{
    __shared__ int lh[NE];
    __shared__ int lbase[NE];
    const int tid = threadIdx.x;
    if (tid < NE) lh[tid] = 0;
    __syncthreads();

    const int b = blockIdx.x * 256 + tid;
    const int e0 = top_e[2*b+0];
    const int e1 = top_e[2*b+1];
    atomicAdd(&lh[e0], 1);
    atomicAdd(&lh[e1], 1);
    __syncthreads();
    if (tid < NE) {
        lbase[tid] = atomicAdd(&cur[tid], lh[tid]);
        lh[tid] = 0;
    }
    __syncthreads();
    int r0 = atomicAdd(&lh[e0], 1);
    int p0 = lbase[e0] + r0;
    pair_b[p0] = b; pair_w[p0] = top_w[2*b+0];
    int r1 = atomicAdd(&lh[e1], 1);
    int p1 = lbase[e1] + r1;
    pair_b[p1] = b; pair_w[p1] = top_w[2*b+1];
}

// ---------------- expert compute: fc1+gelu, LN, fc2; out += w * lpe ----------------
#define EXP_BX 64
__global__ __launch_bounds__(256, 2) void k_expert(
    const float* __restrict__ h,
    const int* __restrict__ pair_b, const float* __restrict__ pair_w,
    const int* __restrict__ hist, const int* __restrict__ offs,
    const float* __restrict__ ew1, const float* __restrict__ eb1,
    const float* __restrict__ eg, const float* __restrict__ ebeta,
    const float* __restrict__ ew2, const float* __restrict__ eb2,
    float* __restrict__ out)
{
    const int e = blockIdx.y;
    const int cnt = hist[e];
    if ((int)(blockIdx.x * 256) >= cnt) return;

    __shared__ __align__(16) float s_w1[EMB * EMB];    // 16 KB
    __shared__ __align__(16) float s_w2p[EMB * W2P];   // 3 KB
    __shared__ __align__(16) float s_b1[EMB];
    __shared__ __align__(16) float s_g[EMB];
    __shared__ __align__(16) float s_be[EMB];
    __shared__ __align__(16) float s_b2p[W2P];

    const int tid = threadIdx.x;
    for (int i = tid; i < EMB * EMB; i += 256) s_w1[i] = ew1[(size_t)e * EMB * EMB + i];
    for (int i = tid; i < EMB * W2P; i += 256) {
        int k = i / W2P, c = i - k * W2P;
        s_w2p[i] = (c < NCLS) ? ew2[((size_t)e * EMB + k) * NCLS + c] : 0.0f;
    }
    if (tid < EMB) { s_b1[tid] = eb1[e * EMB + tid]; s_g[tid] = eg[e * EMB + tid]; s_be[tid] = ebeta[e * EMB + tid]; }
    if (tid < W2P) s_b2p[tid] = (tid < NCLS) ? eb2[e * NCLS + tid] : 0.0f;
    __syncthreads();

    const int base = offs[e];
    for (int lane = blockIdx.x * 256 + tid; lane < cnt; lane += EXP_BX * 256) {
        const int idx = base + lane;
        const int b = pair_b[idx];
        const float pw = pair_w[idx];

        float hreg[EMB];
        const float4* hp = (const float4*)(h + (size_t)b * EMB);
#pragma unroll
        for (int t = 0; t < EMB / 4; ++t) {
            float4 v = hp[t];
            hreg[4*t+0] = v.x; hreg[4*t+1] = v.y; hreg[4*t+2] = v.z; hreg[4*t+3] = v.w;
        }

        float z[EMB];
        {
            const float4* sw = (const float4*)s_w1;
            const float4* sb = (const float4*)s_b1;
#pragma unroll
            for (int k0 = 0; k0 < EMB / 4; ++k0) {
                float4 a = sb[k0];
#pragma unroll
                for (int d = 0; d < EMB; ++d) {
                    float4 w = sw[d * (EMB / 4) + k0];
                    a.x = fmaf(hreg[d], w.x, a.x);
                    a.y = fmaf(hreg[d], w.y, a.y);
                    a.z = fmaf(hreg[d], w.z, a.z);
                    a.w = fmaf(hreg[d], w.w, a.w);
                }
                z[4*k0+0] = gelu_f(a.x); z[4*k0+1] = gelu_f(a.y);
                z[4*k0+2] = gelu_f(a.z); z[4*k0+3] = gelu_f(a.w);
            }
        }

        float mu = 0.0f;
#pragma unroll
        for (int k = 0; k < EMB; ++k) mu += z[k];
        mu *= (1.0f / EMB);
        float var = 0.0f;
#pragma unroll
        for (int k = 0; k < EMB; ++k) { float t = z[k] - mu; var = fmaf(t, t, var); }
        var *= (1.0f / EMB);
        float inv = 1.0f / sqrtf(var + 1e-5f);
#pragma unroll
        for (int k = 0; k < EMB; ++k) z[k] = (z[k] - mu) * inv * s_g[k] + s_be[k];

        float a[W2P];
#pragma unroll
        for (int c = 0; c < W2P; ++c) a[c] = s_b2p[c];
        const float4* sw2 = (const float4*)s_w2p;
#pragma unroll
        for (int k = 0; k < EMB; ++k) {
            float zk = z[k];
            float4 q0 = sw2[k * 3 + 0];
            float4 q1 = sw2[k * 3 + 1];
            float4 q2 = sw2[k * 3 + 2];
            a[0] = fmaf(zk, q0.x, a[0]); a[1] = fmaf(zk, q0.y, a[1]);
            a[2] = fmaf(zk, q0.z, a[2]); a[3] = fmaf(zk, q0.w, a[3]);
            a[4] = fmaf(zk, q1.x, a[4]); a[5] = fmaf(zk, q1.y, a[5]);
            a[6] = fmaf(zk, q1.z, a[6]); a[7] = fmaf(zk, q1.w, a[7]);
            a[8] = fmaf(zk, q2.x, a[8]); a[9] = fmaf(zk, q2.y, a[9]);
        }
#pragma unroll
        for (int c = 0; c < NCLS; ++c)
            atomicAdd(out + (size_t)b * NCLS + c, pw * a[c]);
    }
}

extern "C" void kernel_launch(void* const* d_in, const int* in_sizes, int n_in,
                              void* d_out, int out_size, void* d_ws, size_t ws_size,
                              hipStream_t stream)
{
    (void)in_sizes; (void)n_in; (void)out_size; (void)ws_size;

    const float* x     = (const float*)d_in[0];
    const int*   uid   = (const int*)  d_in[1];
    const float* bb_w1 = (const float*)d_in[2];
    const float* bb_b1 = (const float*)d_in[3];
    const float* bb_w2 = (const float*)d_in[4];
    const float* bb_b2 = (const float*)d_in[5];
    const float* bb_g  = (const float*)d_in[6];
    const float* bb_be = (const float*)d_in[7];
    const float* gU    = (const float*)d_in[8];
    const float* gV    = (const float*)d_in[9];
    const float* gb    = (const float*)d_in[10];
    const float* e_w1  = (const float*)d_in[11];
    const float* e_b1  = (const float*)d_in[12];
    const float* e_g   = (const float*)d_in[13];
    const float* e_be  = (const float*)d_in[14];
    const float* e_w2  = (const float*)d_in[15];
    const float* e_b2  = (const float*)d_in[16];
    const float* ut    = (const float*)d_in[17];

    float* out = (float*)d_out;
    char*  ws  = (char*)d_ws;

    float* h      = (float*)(ws + OFF_H);
    float* A      = (float*)(ws + OFF_A);
    int*   top_e  = (int*)  (ws + OFF_TOPE);
    float* top_w  = (float*)(ws + OFF_TOPW);
    int*   pair_b = (int*)  (ws + OFF_PAIRB);
    float* pair_w = (float*)(ws + OFF_PAIRW);
    int*   hist   = (int*)  (ws + OFF_HIST);
    int*   offs   = (int*)  (ws + OFF_OFFS);
    int*   cur    = (int*)  (ws + OFF_CUR);

    hipMemsetAsync(out, 0, (size_t)BATCH * NCLS * sizeof(float), stream);
    hipMemsetAsync(hist, 0, NE * sizeof(int), stream);

    k_prep<<<(NUSERS * NE + 255) / 256, 256, 0, stream>>>(gU, gV, ut, A);
    k_fused<<<BATCH / 256, 256, 0, stream>>>(x, uid, bb_w1, bb_b1, bb_w2, bb_b2,
                                             bb_g, bb_be, A, gb, h, top_e, top_w, hist);
    k_scan<<<1, 64, 0, stream>>>(hist, offs, cur);
    k_scatter<<<BATCH / 256, 256, 0, stream>>>(top_e, top_w, cur, pair_b, pair_w);
    dim3 eg(EXP_BX, NE);
    k_expert<<<eg, 256, 0, stream>>>(h, pair_b, pair_w, hist, offs,
                                     e_w1, e_b1, e_g, e_be, e_w2, e_b2, out);
}